// Round 5
// baseline (252.546 us; speedup 1.0000x reference)
//
#include <hip/hip_runtime.h>

#define BIGF 1e8f
static constexpr int NSEQ = 512;
static constexpr int BAND = 50;
static constexpr int NB = 32;

// lane l <- lane (l-1)&63 : DPP wavefront rotate-right-by-1 (gfx9 ctrl 0x13C).
// MUST be executed at full exec (never inside divergent control flow): a
// disabled SOURCE lane makes DPP return `old` (0 here). R4's failure was
// exactly this — rotup1 inside a ternary branch.
__device__ __forceinline__ float rotup1(float v) {
  return __int_as_float(__builtin_amdgcn_update_dpp(
      0, __float_as_int(v), 0x13C, 0xf, 0xf, false));
}

// One wave per DP problem. k&31 = batch, k>>5 = type (0:xy, 1:xx, 2:yy).
// Row i on lane i&63 (invariant i = ilo + ((l-ilo)&63)).
// r1 = masked diag d-1, upp = rot1(masked diag d-2) (= "up" of prev step).
// No LDS in the loop:
//   bv (= b[d-i], float4) propagates lane-to-lane by ROR1; one wave-uniform
//     injection b[d-ilo] into the bottom lane per step (redundant-but-equal
//     on jump steps). Jumped (top) lane's bv is stale for one step while
//     provably inactive, and self-corrects the next step.
//   av (= a[i]) changes only at row jumps: inject wave-uniform
//     a[min(511, ilo+63)] into the top lane (no-op on non-jump steps).
// Injection values have scalar addresses f(d) -> prefetched 7 steps ahead
// into named rotating slots (unroll 7; 1022 = 7*146 exactly).
__global__ __launch_bounds__(64) void softdtw_band_kernel(
    const float* __restrict__ x, const float* __restrict__ y,
    float* __restrict__ ws)
{
  const int k = blockIdx.x;
  const int batch = k & (NB - 1);
  const int type = k >> 5;
  const float4* Aq = (const float4*)((type == 2 ? y : x) + (size_t)batch * NSEQ * 4);
  const float4* Bq = (const float4*)((type == 1 ? x : y) + (size_t)batch * NSEQ * 4);

  const int l = threadIdx.x;
  const float K1 = 0.721347520444482f;  // 1/(gamma*ln2), gamma=2
  const float K2 = 1.386294361119891f;  // gamma*ln2

  float4 av = Aq[l];      // a[i], i=l
  float4 bv = Bq[0];      // seed: only lane 0's value matters (b[0])
  float4 a63 = Aq[63];

  // Slots for steps d=1..7 (ilo=0 there): na = a[63], nb = b[d].
  float4 na0=a63, na1=a63, na2=a63, na3=a63, na4=a63, na5=a63, na6=a63;
  float4 nb0=Bq[1], nb1=Bq[2], nb2=Bq[3], nb3=Bq[4], nb4=Bq[5], nb5=Bq[6], nb6=Bq[7];

  // d = 0 seed: R[0,0] = D(0,0)
  float e0 = av.x - bv.x, e1 = av.y - bv.y, e2 = av.z - bv.z, e3 = av.w - bv.w;
  float dv00 = (e0 * e0 + e1 * e1) + (e2 * e2 + e3 * e3);
  float r1 = (l == 0) ? dv00 : BIGF;
  float upp = BIGF;
  int i = l;

#define STEP(D, NA, NBv)                                                       \
  {                                                                            \
    const int d_ = (D);                                                        \
    const int ilo_ = max(max(0, d_ - (NSEQ-1)), max(0, d_ - (BAND-1)) >> 1);   \
    const int ihi_ = min(min(NSEQ-1, d_), (d_ + BAND) >> 1);                   \
    i += (i < ilo_) ? 64 : 0;                                                  \
    const bool bot = (i == ilo_);                                              \
    const bool top = (i == ilo_ + 63);                                         \
    /* DPPs first, unconditional, full exec: */                                \
    float rbx_ = rotup1(bv.x);                                                 \
    float rby_ = rotup1(bv.y);                                                 \
    float rbz_ = rotup1(bv.z);                                                 \
    float rbw_ = rotup1(bv.w);                                                 \
    float up = rotup1(r1);                                                     \
    /* pure register selects (v_cndmask), no convergent op inside: */          \
    bv.x = bot ? NBv.x : rbx_;                                                 \
    bv.y = bot ? NBv.y : rby_;                                                 \
    bv.z = bot ? NBv.z : rbz_;                                                 \
    bv.w = bot ? NBv.w : rbw_;                                                 \
    av.x = top ? NA.x : av.x;                                                  \
    av.y = top ? NA.y : av.y;                                                  \
    av.z = top ? NA.z : av.z;                                                  \
    av.w = top ? NA.w : av.w;                                                  \
    float ddx = av.x - bv.x, ddy = av.y - bv.y,                                \
          ddz = av.z - bv.z, ddw = av.w - bv.w;                                \
    float dv = ddx * ddx;                                                      \
    dv = __builtin_fmaf(ddy, ddy, dv);                                         \
    dv = __builtin_fmaf(ddz, ddz, dv);                                         \
    dv = __builtin_fmaf(ddw, ddw, dv);                                         \
    float dg = upp;                                                            \
    float left = r1;                                                           \
    float mn = fminf(fminf(up, left), dg);                                     \
    float mk = mn * K1;                                                        \
    float ssum = __builtin_exp2f(__builtin_fmaf(-K1, up, mk))                  \
               + __builtin_exp2f(__builtin_fmaf(-K1, left, mk))                \
               + __builtin_exp2f(__builtin_fmaf(-K1, dg, mk));                 \
    float rr = __builtin_fmaf(-K2, __builtin_log2f(ssum), mn + dv);            \
    r1 = (i <= ihi_) ? rr : BIGF;                                              \
    upp = up;                                                                  \
    const int d7_ = d_ + 7;                                                    \
    const int ilo7_ = max(max(0, d7_ - (NSEQ-1)), max(0, d7_ - (BAND-1)) >> 1);\
    NA = Aq[min(NSEQ-1, ilo7_ + 63)];                                          \
    NBv = Bq[d7_ - ilo7_];                                                     \
  }

  // d = 1 .. 1022 = 7 * 146 steps exactly.
  for (int mm = 0; mm < 146; ++mm) {
    const int d = 7 * mm;
    STEP(d + 1, na0, nb0);
    STEP(d + 2, na1, nb1);
    STEP(d + 3, na2, nb2);
    STEP(d + 4, na3, nb3);
    STEP(d + 5, na4, nb4);
    STEP(d + 6, na5, nb5);
    STEP(d + 7, na6, nb6);
  }
#undef STEP

  // R[511,511]: ilo(1022)=511 -> lane 511&63 = 63, active (ihi=511).
  if (l == 63) ws[k] = r1;
}

__global__ void softdtw_combine_kernel(const float* __restrict__ ws,
                                       float* __restrict__ out) {
  int b = threadIdx.x;
  if (b < NB) out[b] = ws[b] - 0.5f * (ws[NB + b] + ws[2 * NB + b]);
}

extern "C" void kernel_launch(void* const* d_in, const int* in_sizes, int n_in,
                              void* d_out, int out_size, void* d_ws, size_t ws_size,
                              hipStream_t stream) {
  const float* x = (const float*)d_in[0];
  const float* y = (const float*)d_in[1];
  float* ws = (float*)d_ws;
  float* out = (float*)d_out;
  softdtw_band_kernel<<<3 * NB, 64, 0, stream>>>(x, y, ws);
  softdtw_combine_kernel<<<1, 64, 0, stream>>>(ws, out);
}

// Round 6
// 196.439 us; speedup vs baseline: 1.2856x; 1.2856x over previous
//
#include <hip/hip_runtime.h>

#define BIGF 1e8f
static constexpr int NSEQ = 512;
static constexpr int BAND = 50;
static constexpr int NB = 32;

// lane l <- lane (l-1)&63 : DPP wavefront rotate-right-by-1 (gfx9 ctrl 0x13C).
// MUST execute at full exec (disabled source lane would yield old=0).
__device__ __forceinline__ float rotup1(float v) {
  return __int_as_float(__builtin_amdgcn_update_dpp(
      0, __float_as_int(v), 0x13C, 0xf, 0xf, false));
}

// One wave per DP problem. k&31 = batch, k>>5 = type (0:xy, 1:xx, 2:yy).
// Row i on lane i&63 (invariant i = ilo + ((l-ilo)&63)).
// r1 = masked diag d-1, upp = rot1(masked diag d-2) (= "up" of prev step).
// Operands ride the same ROR1 rotate chain as the DP (R5, verified):
//   bv = b[d-i] propagates lane-to-lane; wave-uniform injection b[d-ilo]
//   into the bottom lane each step. av = a[i] changes only at row jumps:
//   inject wave-uniform a[min(511, ilo+63)] into the top lane.
// R6 fix vs R5: injection values come from LDS (in-order DS returns ->
// counted lgkmcnt, pipeline survives), via UNIFORM-address ds_read_b128
// broadcasts — not global s_load (SMEM is out-of-order; its lgkmcnt(0)
// drain serialized R5 at ~595 cy/step).
__global__ __launch_bounds__(64) void softdtw_band_kernel(
    const float* __restrict__ x, const float* __restrict__ y,
    float* __restrict__ ws)
{
  const int k = blockIdx.x;
  const int batch = k & (NB - 1);
  const int type = k >> 5;
  const float4* Aq = (const float4*)((type == 2 ? y : x) + (size_t)batch * NSEQ * 4);
  const float4* Bq = (const float4*)((type == 1 ? x : y) + (size_t)batch * NSEQ * 4);

  __shared__ float4 sa[NSEQ];
  __shared__ float4 sb[NSEQ];

  const int l = threadIdx.x;
  #pragma unroll
  for (int q = 0; q < NSEQ / 64; ++q) {
    sa[l + q * 64] = Aq[l + q * 64];
    sb[l + q * 64] = Bq[l + q * 64];
  }
  __syncthreads();

  const float K1 = 0.721347520444482f;  // 1/(gamma*ln2), gamma=2
  const float K2 = 1.386294361119891f;  // gamma*ln2

  float4 av = sa[l];      // a[i], i=l
  float4 bv = sb[0];      // seed: only lane 0's value matters (b[0])
  float4 a63 = sa[63];

  // Slots for steps d=1..7 (ilo=0 there): na = a[63], nb = b[d].
  float4 na0=a63, na1=a63, na2=a63, na3=a63, na4=a63, na5=a63, na6=a63;
  float4 nb0=sb[1], nb1=sb[2], nb2=sb[3], nb3=sb[4], nb4=sb[5], nb5=sb[6], nb6=sb[7];

  // d = 0 seed: R[0,0] = D(0,0)
  float e0 = av.x - bv.x, e1 = av.y - bv.y, e2 = av.z - bv.z, e3 = av.w - bv.w;
  float dv00 = (e0 * e0 + e1 * e1) + (e2 * e2 + e3 * e3);
  float r1 = (l == 0) ? dv00 : BIGF;
  float upp = BIGF;
  int i = l;

#define STEP(D, NA, NBv)                                                       \
  {                                                                            \
    const int d_ = (D);                                                        \
    const int ilo_ = max(max(0, d_ - (NSEQ-1)), max(0, d_ - (BAND-1)) >> 1);   \
    const int ihi_ = min(min(NSEQ-1, d_), (d_ + BAND) >> 1);                   \
    i += (i < ilo_) ? 64 : 0;                                                  \
    const bool bot = (i == ilo_);                                              \
    const bool top = (i == ilo_ + 63);                                         \
    /* DPPs first, unconditional, full exec: */                                \
    float rbx_ = rotup1(bv.x);                                                 \
    float rby_ = rotup1(bv.y);                                                 \
    float rbz_ = rotup1(bv.z);                                                 \
    float rbw_ = rotup1(bv.w);                                                 \
    float up = rotup1(r1);                                                     \
    /* pure register selects (v_cndmask), no convergent op inside: */          \
    bv.x = bot ? NBv.x : rbx_;                                                 \
    bv.y = bot ? NBv.y : rby_;                                                 \
    bv.z = bot ? NBv.z : rbz_;                                                 \
    bv.w = bot ? NBv.w : rbw_;                                                 \
    av.x = top ? NA.x : av.x;                                                  \
    av.y = top ? NA.y : av.y;                                                  \
    av.z = top ? NA.z : av.z;                                                  \
    av.w = top ? NA.w : av.w;                                                  \
    float ddx = av.x - bv.x, ddy = av.y - bv.y,                                \
          ddz = av.z - bv.z, ddw = av.w - bv.w;                                \
    float dv = ddx * ddx;                                                      \
    dv = __builtin_fmaf(ddy, ddy, dv);                                         \
    dv = __builtin_fmaf(ddz, ddz, dv);                                         \
    dv = __builtin_fmaf(ddw, ddw, dv);                                         \
    float dg = upp;                                                            \
    float left = r1;                                                           \
    float mn = fminf(fminf(up, left), dg);                                     \
    float mk = mn * K1;                                                        \
    float ssum = __builtin_exp2f(__builtin_fmaf(-K1, up, mk))                  \
               + __builtin_exp2f(__builtin_fmaf(-K1, left, mk))                \
               + __builtin_exp2f(__builtin_fmaf(-K1, dg, mk));                 \
    float rr = __builtin_fmaf(-K2, __builtin_log2f(ssum), mn + dv);            \
    r1 = (i <= ihi_) ? rr : BIGF;                                              \
    upp = up;                                                                  \
    /* refill slot for step d+7 from LDS, uniform address (broadcast): */      \
    const int d7_ = d_ + 7;                                                    \
    const int ilo7_ = max(max(0, d7_ - (NSEQ-1)), max(0, d7_ - (BAND-1)) >> 1);\
    NA = sa[min(NSEQ-1, ilo7_ + 63)];                                          \
    NBv = sb[d7_ - ilo7_];                                                     \
  }

  // d = 1 .. 1022 = 7 * 146 steps exactly.
  for (int mm = 0; mm < 146; ++mm) {
    const int d = 7 * mm;
    STEP(d + 1, na0, nb0);
    STEP(d + 2, na1, nb1);
    STEP(d + 3, na2, nb2);
    STEP(d + 4, na3, nb3);
    STEP(d + 5, na4, nb4);
    STEP(d + 6, na5, nb5);
    STEP(d + 7, na6, nb6);
  }
#undef STEP

  // R[511,511]: ilo(1022)=511 -> lane 511&63 = 63, active (ihi=511).
  if (l == 63) ws[k] = r1;
}

__global__ void softdtw_combine_kernel(const float* __restrict__ ws,
                                       float* __restrict__ out) {
  int b = threadIdx.x;
  if (b < NB) out[b] = ws[b] - 0.5f * (ws[NB + b] + ws[2 * NB + b]);
}

extern "C" void kernel_launch(void* const* d_in, const int* in_sizes, int n_in,
                              void* d_out, int out_size, void* d_ws, size_t ws_size,
                              hipStream_t stream) {
  const float* x = (const float*)d_in[0];
  const float* y = (const float*)d_in[1];
  float* ws = (float*)d_ws;
  float* out = (float*)d_out;
  softdtw_band_kernel<<<3 * NB, 64, 0, stream>>>(x, y, ws);
  softdtw_combine_kernel<<<1, 64, 0, stream>>>(ws, out);
}

// Round 7
// 162.462 us; speedup vs baseline: 1.5545x; 1.2091x over previous
//
#include <hip/hip_runtime.h>

#define BIGF 1e8f
static constexpr int NSEQ = 512;
static constexpr int NB = 32;

// lane l <- lane (l-1)&63 : DPP wavefront rotate-right-by-1 (gfx9 ctrl 0x13C).
// Must execute at full exec (disabled source lane would yield old=0).
__device__ __forceinline__ float rotup1(float v) {
  return __int_as_float(__builtin_amdgcn_update_dpp(
      0, __float_as_int(v), 0x13C, 0xf, 0xf, false));
}
// Wave-uniform read of lane `idx` (dynamic uniform index) — no memory, no waitcnt.
__device__ __forceinline__ float rlane(float v, int idx) {
  return __int_as_float(__builtin_amdgcn_readlane(__float_as_int(v), idx));
}

// One wave per DP problem. k&31 = batch, k>>5 = type (0:xy, 1:xx, 2:yy).
// Row i on lane i&63; r1 = masked diag d-1, upp = rot1(masked diag d-2).
// Operands ride ROR1 rotate chains (verified R5/R6). R7: ZERO memory ops in
// the steady loop — injection values come from 64-wide REGISTER windows
// (W[l] = seq[base+l]) via v_readlane with a uniform walking index; windows
// double-buffer and refill once per 128 steps with coalesced global loads.
// Phase split (exact index arithmetic, no min/max chains in-loop):
//  P1: d=1..50      ilo=0, binj=b[d] from bseed window, no a-injection.
//  P2: d=51..946    448 two-step macros m=0..447 in 7 epochs of 64:
//                   ilo=m+1, jA=50+m (prev macro's value), jB=51+m (idx m2),
//                   a_idx=64+m (idx m2). Window bases advance 64/epoch.
//  P2t: d=947..972  13 macros m=448..460, b from epoch-7 window, a=a[511].
//  P3: d=973..1022  ilo=d-511, both injections const a[511], b[511].
__global__ __launch_bounds__(64) void softdtw_band_kernel(
    const float* __restrict__ x, const float* __restrict__ y,
    float* __restrict__ ws)
{
  const int k = blockIdx.x;
  const int batch = k & (NB - 1);
  const int type = k >> 5;
  const float4* Aq = (const float4*)((type == 2 ? y : x) + (size_t)batch * NSEQ * 4);
  const float4* Bq = (const float4*)((type == 1 ? x : y) + (size_t)batch * NSEQ * 4);

  const int l = threadIdx.x;
  const float K1 = 0.721347520444482f;  // 1/(gamma*ln2), gamma=2
  const float K2 = 1.386294361119891f;  // gamma*ln2

  float4 av    = Aq[l];        // a[i], i=l
  float4 bseed = Bq[l];        // b[0..63] register window (P1 injections)
  float4 w1a   = Aq[64 + l];   // epoch-0 a-window: a[64..127]
  float4 w1b   = Bq[51 + l];   // epoch-0 b-window: b[51..114]
  float4 w2a = w1a, w2b = w1b; // alternate window set (filled by E0 refill)

  // bv seed: uniform b[0] (only lane 0's value matters at d=0).
  float4 bv;
  bv.x = rlane(bseed.x, 0); bv.y = rlane(bseed.y, 0);
  bv.z = rlane(bseed.z, 0); bv.w = rlane(bseed.w, 0);

  // d=0 seed: R[0,0] = D(0,0) on lane 0.
  float e0 = av.x - bv.x, e1 = av.y - bv.y, e2 = av.z - bv.z, e3 = av.w - bv.w;
  float dv00 = (e0 * e0 + e1 * e1) + (e2 * e2 + e3 * e3);
  float r1 = (l == 0) ? dv00 : BIGF;
  float upp = BIGF;
  int i = l;

// Generic verified step: ILO/IHI wave-uniform ints; BJ/AJ uniform float4
// injection values. DPPs unconditional at full exec; selects are cndmask.
#define STEP(ILO, IHI, BJ, AJ)                                                 \
  {                                                                            \
    const int ilo_ = (ILO);                                                    \
    const int ihi_ = (IHI);                                                    \
    i += (i < ilo_) ? 64 : 0;                                                  \
    const bool bot = (i == ilo_);                                              \
    const bool top = (i == ilo_ + 63);                                         \
    float rbx_ = rotup1(bv.x);                                                 \
    float rby_ = rotup1(bv.y);                                                 \
    float rbz_ = rotup1(bv.z);                                                 \
    float rbw_ = rotup1(bv.w);                                                 \
    float up = rotup1(r1);                                                     \
    bv.x = bot ? (BJ).x : rbx_;                                                \
    bv.y = bot ? (BJ).y : rby_;                                                \
    bv.z = bot ? (BJ).z : rbz_;                                                \
    bv.w = bot ? (BJ).w : rbw_;                                                \
    av.x = top ? (AJ).x : av.x;                                                \
    av.y = top ? (AJ).y : av.y;                                                \
    av.z = top ? (AJ).z : av.z;                                                \
    av.w = top ? (AJ).w : av.w;                                                \
    float ddx = av.x - bv.x, ddy = av.y - bv.y,                                \
          ddz = av.z - bv.z, ddw = av.w - bv.w;                                \
    float dv = ddx * ddx;                                                      \
    dv = __builtin_fmaf(ddy, ddy, dv);                                         \
    dv = __builtin_fmaf(ddz, ddz, dv);                                         \
    dv = __builtin_fmaf(ddw, ddw, dv);                                         \
    float dg = upp;                                                            \
    float left = r1;                                                           \
    float mn = fminf(fminf(up, left), dg);                                     \
    float mk = mn * K1;                                                        \
    float ssum = __builtin_exp2f(__builtin_fmaf(-K1, up, mk))                  \
               + __builtin_exp2f(__builtin_fmaf(-K1, left, mk))                \
               + __builtin_exp2f(__builtin_fmaf(-K1, dg, mk));                 \
    float rr = __builtin_fmaf(-K2, __builtin_log2f(ssum), mn + dv);            \
    r1 = (i <= ihi_) ? rr : BIGF;                                              \
    upp = up;                                                                  \
  }

  // ---- Phase 1: d = 1..50 (ilo=0, ihi=d, binj=b[d], ainj=a[63] no-op) ----
  float4 aP1;
  aP1.x = rlane(av.x, 63); aP1.y = rlane(av.y, 63);
  aP1.z = rlane(av.z, 63); aP1.w = rlane(av.w, 63);
  #pragma unroll 2
  for (int d = 1; d <= 50; ++d) {
    float4 bj;
    bj.x = rlane(bseed.x, d); bj.y = rlane(bseed.y, d);
    bj.z = rlane(bseed.z, d); bj.w = rlane(bseed.w, d);
    STEP(0, d, bj, aP1);
  }
  float4 bprev;  // b[50] = j_A of macro m=0
  bprev.x = rlane(bseed.x, 50); bprev.y = rlane(bseed.y, 50);
  bprev.z = rlane(bseed.z, 50); bprev.w = rlane(bseed.w, 50);

  // ---- Phase 2: 7 epochs x 64 macros (d = 51..946) ----
  // CW = current windows (a base 64+64E, b base 51+64E); NW refilled for E+1.
#define EPOCH(E, CWA, CWB, NWA, NWB)                                           \
  {                                                                            \
    NWA = Aq[min(NSEQ - 1, 64 + 64 * ((E) + 1) + l)];                          \
    NWB = Bq[min(NSEQ - 1, 51 + 64 * ((E) + 1) + l)];                          \
    _Pragma("unroll 4")                                                        \
    for (int m2 = 0; m2 < 64; ++m2) {                                          \
      const int m = 64 * (E) + m2;                                             \
      float4 bnew, anew;                                                       \
      bnew.x = rlane(CWB.x, m2); bnew.y = rlane(CWB.y, m2);                    \
      bnew.z = rlane(CWB.z, m2); bnew.w = rlane(CWB.w, m2);                    \
      anew.x = rlane(CWA.x, m2); anew.y = rlane(CWA.y, m2);                    \
      anew.z = rlane(CWA.z, m2); anew.w = rlane(CWA.w, m2);                    \
      STEP(m + 1, m + 50, bprev, anew);   /* d = 51+2m */                      \
      STEP(m + 1, m + 51, bnew, anew);    /* d = 52+2m */                      \
      bprev = bnew;                                                            \
    }                                                                          \
  }

  EPOCH(0, w1a, w1b, w2a, w2b)
  EPOCH(1, w2a, w2b, w1a, w1b)
  EPOCH(2, w1a, w1b, w2a, w2b)
  EPOCH(3, w2a, w2b, w1a, w1b)
  EPOCH(4, w1a, w1b, w2a, w2b)
  EPOCH(5, w2a, w2b, w1a, w1b)
  EPOCH(6, w1a, w1b, w2a, w2b)   // refills w2 = epoch-7 windows (b[499..511])
#undef EPOCH

  // Constants for the tail: a[511] (E6 a-window idx 63), b[511] (w2b idx 12).
  float4 a3, b511;
  a3.x = rlane(w1a.x, 63); a3.y = rlane(w1a.y, 63);
  a3.z = rlane(w1a.z, 63); a3.w = rlane(w1a.w, 63);
  b511.x = rlane(w2b.x, 12); b511.y = rlane(w2b.y, 12);
  b511.z = rlane(w2b.z, 12); b511.w = rlane(w2b.w, 12);

  // ---- Phase 2t: macros m = 448..460 (d = 947..972), a-injection = a[511] ----
  #pragma unroll 2
  for (int m = 448; m <= 460; ++m) {
    float4 bnew;
    bnew.x = rlane(w2b.x, m - 448); bnew.y = rlane(w2b.y, m - 448);
    bnew.z = rlane(w2b.z, m - 448); bnew.w = rlane(w2b.w, m - 448);
    STEP(m + 1, m + 50, bprev, a3);
    STEP(m + 1, m + 51, bnew, a3);
    bprev = bnew;
  }

  // ---- Phase 3: d = 973..1022 (ilo = d-511, ihi = 511, const injections) ----
  #pragma unroll 2
  for (int d = 973; d <= 1022; ++d) {
    STEP(d - 511, NSEQ - 1, b511, a3);
  }
#undef STEP

  // R[511,511]: row 511 on lane 63.
  if (l == 63) ws[k] = r1;
}

__global__ void softdtw_combine_kernel(const float* __restrict__ ws,
                                       float* __restrict__ out) {
  int b = threadIdx.x;
  if (b < NB) out[b] = ws[b] - 0.5f * (ws[NB + b] + ws[2 * NB + b]);
}

extern "C" void kernel_launch(void* const* d_in, const int* in_sizes, int n_in,
                              void* d_out, int out_size, void* d_ws, size_t ws_size,
                              hipStream_t stream) {
  const float* x = (const float*)d_in[0];
  const float* y = (const float*)d_in[1];
  float* ws = (float*)d_ws;
  float* out = (float*)d_out;
  softdtw_band_kernel<<<3 * NB, 64, 0, stream>>>(x, y, ws);
  softdtw_combine_kernel<<<1, 64, 0, stream>>>(ws, out);
}